// Round 9
// baseline (375.014 us; speedup 1.0000x reference)
//
#include <hip/hip_runtime.h>
#include <stdint.h>

typedef unsigned int u32;
typedef unsigned long long u64;

#define BN 8
#define HW_ 65536
#define N1 196608
#define NOPS_ 65536
#define NROWS_ 24576
#define NB1 192
#define NB2 64
#define LBW 32

// ---------------- sort key transform ----------------
__device__ __forceinline__ u32 fkey(float x) {
  u32 u = __float_as_uint(x);
  return u ^ ((u & 0x80000000u) ? 0xFFFFFFFFu : 0x80000000u);
}

__device__ __forceinline__ u32 wscan_incl(u32 x, int lane) {
#pragma unroll
  for (int off = 1; off < 64; off <<= 1) {
    u32 y = __shfl_up(x, off, 64);
    if (lane >= off) x += y;
  }
  return x;
}

// ---------------- upfront: all-4-pass global digit totals (one key read) ----------------
// sort 1: from logits. grid = BN*96, 2048 items/block
__global__ __launch_bounds__(256) void histAll1(const float* __restrict__ xf, u32* __restrict__ gTot) {
  __shared__ u32 h[4][256];
  int t = threadIdx.x;
  int b = blockIdx.x / 96, chunk = blockIdx.x % 96;
#pragma unroll
  for (int p = 0; p < 4; ++p) h[p][t] = 0;
  __syncthreads();
  const float* xp = xf + (size_t)b * N1 + (size_t)chunk * 2048;
#pragma unroll
  for (int j = 0; j < 8; ++j) {
    u32 k = fkey(xp[j * 256 + t]);
    atomicAdd(&h[0][k & 255u], 1u);
    atomicAdd(&h[1][(k >> 8) & 255u], 1u);
    atomicAdd(&h[2][(k >> 16) & 255u], 1u);
    atomicAdd(&h[3][k >> 24], 1u);
  }
  __syncthreads();
#pragma unroll
  for (int p = 0; p < 4; ++p) {
    u32 v = h[p][t];
    if (v) atomicAdd(&gTot[((size_t)p * BN + b) * 256 + t], v);   // per-digit atomics: deterministic
  }
}

// sort 2: from kv2 keys. grid = BN*64, 1024 items/block
__global__ __launch_bounds__(256) void histAll2(const u64* __restrict__ kv, u32* __restrict__ gTot) {
  __shared__ u32 h[4][256];
  int t = threadIdx.x;
  int b = blockIdx.x / 64, chunk = blockIdx.x % 64;
#pragma unroll
  for (int p = 0; p < 4; ++p) h[p][t] = 0;
  __syncthreads();
  const u64* kp = kv + (size_t)b * NOPS_ + (size_t)chunk * 1024;
#pragma unroll
  for (int j = 0; j < 4; ++j) {
    u32 k = (u32)(kp[j * 256 + t] >> 32);
    atomicAdd(&h[0][k & 255u], 1u);
    atomicAdd(&h[1][(k >> 8) & 255u], 1u);
    atomicAdd(&h[2][(k >> 16) & 255u], 1u);
    atomicAdd(&h[3][k >> 24], 1u);
  }
  __syncthreads();
#pragma unroll
  for (int p = 0; p < 4; ++p) {
    u32 v = h[p][t];
    if (v) atomicAdd(&gTot[((size_t)p * BN + b) * 256 + t], v);
  }
}

// exclusive scan of each 256-digit total vector. grid = nvec blocks, 64 threads
__global__ void scanTot(const u32* __restrict__ gTot, u32* __restrict__ dBase) {
  int v = blockIdx.x, t = threadIdx.x;
  const u32* gt = gTot + (size_t)v * 256;
  u32* db = dBase + (size_t)v * 256;
  u32 run = 0;
#pragma unroll
  for (int c = 0; c < 4; ++c) {
    u32 x = gt[c * 64 + t];
    u32 incl = wscan_incl(x, t);
    db[c * 64 + t] = run + incl - x;
    run += __shfl(incl, 63, 64);
  }
}

// ---------------- OneSweep scatter: decoupled-lookback, stable, LDS-staged ----------------
template <bool FIRST, bool FINAL>
__global__ __launch_bounds__(256) void rs_sweep(const u64* __restrict__ kvIn, const float* __restrict__ xf,
                                                u64* __restrict__ out64, u32* __restrict__ out32,
                                                const u32* __restrict__ dBase, u32* __restrict__ lb,
                                                u32* __restrict__ tileCtr, int n, int nblk, int shift) {
  __shared__ u32 sBase[256];
  __shared__ u32 cnt[16][256];   // [strip*4+wave][digit]
  __shared__ u32 dpre[256];
  __shared__ u32 wsum[4];
  __shared__ u64 stage[1024];
  __shared__ u32 tileSh;
  int t = threadIdx.x, lane = t & 63, wid = t >> 6;
  if (t == 0) tileSh = atomicAdd(tileCtr, 1u);
#pragma unroll
  for (int r = 0; r < 16; ++r) cnt[r][t] = 0;
  __syncthreads();
  u32 gt = tileSh;
  int b = gt / nblk, tile = gt % nblk;
  u64 kvr[4]; u32 dg[4];
  if (FIRST) {
    const float* xp = xf + (size_t)b * n + (size_t)tile * 1024;
#pragma unroll
    for (int j = 0; j < 4; ++j) {
      u32 k = fkey(xp[j * 256 + t]);
      kvr[j] = ((u64)k << 32) | (u32)(tile * 1024 + j * 256 + t);
      dg[j] = k & 255u;
    }
  } else {
    const u64* kp = kvIn + (size_t)b * n + (size_t)tile * 1024;
#pragma unroll
    for (int j = 0; j < 4; ++j) {
      kvr[j] = kp[j * 256 + t];
      dg[j] = (u32)(kvr[j] >> (32 + shift)) & 255u;
    }
  }
  u64 lmask = (1ull << lane) - 1ull;
  u32 rw[4];
#pragma unroll
  for (int j = 0; j < 4; ++j) {
    u32 d = dg[j];
    u64 peers = ~0ull;
#pragma unroll
    for (int bit = 0; bit < 8; ++bit) {
      u64 bal = __ballot((d >> bit) & 1);
      peers &= ((d >> bit) & 1) ? bal : ~bal;
    }
    u64 lower = peers & lmask;
    rw[j] = (u32)__popcll(lower);
    if (lower == 0) cnt[j * 4 + wid][d] = (u32)__popcll(peers);
  }
  __syncthreads();
  // per-tile digit totals; publish aggregate ASAP
  u32 tcnt = 0;
#pragma unroll
  for (int r = 0; r < 16; ++r) tcnt += cnt[r][t];
  u32* lbRow = lb + ((size_t)b * nblk + tile) * 256;
  if (tile > 0)
    __hip_atomic_store(&lbRow[t], (1u << 30) | tcnt, __ATOMIC_RELAXED, __HIP_MEMORY_SCOPE_AGENT);
  // windowed decoupled lookback (register window, compile-time indices)
  u32 acc = 0;
  {
    const u32* lbp = lb + (size_t)b * nblk * 256;
    int j = tile - 1;
    bool done = (tile == 0);
    while (!done) {
      u32 vals[LBW];
#pragma unroll
      for (int q = 0; q < LBW; ++q) {
        int jj = j - q;
        vals[q] = (jj >= 0)
            ? __hip_atomic_load(&lbp[(size_t)jj * 256 + t], __ATOMIC_RELAXED, __HIP_MEMORY_SCOPE_AGENT)
            : (2u << 30);
      }
      int adv = 0;
#pragma unroll
      for (int q = 0; q < LBW; ++q) {
        if (adv == q && !done) {
          u32 st = vals[q] >> 30;
          if (st != 0u) {
            acc += vals[q] & 0x3FFFFFFFu;
            ++adv;
            if (st == 2u) done = true;
          }
        }
      }
      j -= adv;
    }
  }
  __hip_atomic_store(&lbRow[t], (2u << 30) | (acc + tcnt), __ATOMIC_RELAXED, __HIP_MEMORY_SCOPE_AGENT);
  sBase[t] = dBase[b * 256 + t] + acc;
  // local per-digit row prefix (item order: strip, wave -> stability)
  u32 run = 0;
#pragma unroll
  for (int r = 0; r < 16; ++r) { u32 c = cnt[r][t]; cnt[r][t] = run; run += c; }
  u32 incl = wscan_incl(run, lane);
  if (lane == 63) wsum[wid] = incl;
  __syncthreads();
  u32 woff = 0;
#pragma unroll
  for (int w = 0; w < 4; ++w) if (w < wid) woff += wsum[w];
  dpre[t] = woff + incl - run;
  __syncthreads();
  // stage into LDS in digit-sorted (final) order
#pragma unroll
  for (int j = 0; j < 4; ++j) {
    u32 d = dg[j];
    stage[dpre[d] + cnt[j * 4 + wid][d] + rw[j]] = kvr[j];
  }
  __syncthreads();
  // coalesced write-out
#pragma unroll
  for (int s = 0; s < 4; ++s) {
    int i = s * 256 + t;
    u64 kv = stage[i];
    u32 d = (u32)(kv >> (32 + shift)) & 255u;
    u32 g = sBase[d] + ((u32)i - dpre[d]);
    if (FINAL) out32[(size_t)b * n + g] = (u32)kv;
    else out64[(size_t)b * n + g] = kv;
  }
}

// ---------------- conv1 (grouped 1->8, 3x3 SAME) + permutation scatter + addr3 build (k==0) ----------------
__global__ __launch_bounds__(256) void conv1_scatter(const u32* __restrict__ addr, const float* __restrict__ w1,
                                                     const float* __restrict__ b1, float* __restrict__ mem,
                                                     uint4* __restrict__ addr3) {
  __shared__ float ax[34][34];
  __shared__ float ws[8][9];
  __shared__ float bs[8];
  int t = threadIdx.x;
  int blk = blockIdx.x;
  int tile = blk & 63; int bk2 = blk >> 6; int k = bk2 % 3; int b = bk2 / 3;
  int ty = tile >> 3, tx = tile & 7;
  if (t < 72) ws[t / 9][t % 9] = w1[k * 72 + t];
  if (t >= 128 && t < 136) bs[t - 128] = b1[k * 8 + (t - 128)];
  const u32* ap = addr + (size_t)b * N1 + (size_t)k * HW_;
  for (int idx = t; idx < 34 * 34; idx += 256) {
    int y = idx / 34, x = idx % 34;
    int h = ty * 32 + y - 1, w = tx * 32 + x - 1;
    float v = 0.f;
    if (h >= 0 && h < 256 && w >= 0 && w < 256) v = (float)ap[h * 256 + w];
    ax[y][x] = v;
  }
  __syncthreads();
  float* mb = mem + (size_t)b * N1 * 8;
  const u32* adb = addr + (size_t)b * N1;
  uint4* a3b = addr3 + (size_t)b * HW_;
#pragma unroll
  for (int s = 0; s < 4; ++s) {
    int p = t + s * 256;
    int y = p >> 5, x = p & 31;
    float f[8];
#pragma unroll
    for (int c = 0; c < 8; ++c) f[c] = bs[c];
#pragma unroll
    for (int dy = 0; dy < 3; ++dy)
#pragma unroll
      for (int dx = 0; dx < 3; ++dx) {
        float v = ax[y + dy][x + dx];
#pragma unroll
        for (int c = 0; c < 8; ++c) f[c] = fmaf(ws[c][dy * 3 + dx], v, f[c]);
      }
    u32 a = (u32)ax[y + 1][x + 1];
    float4* dst = reinterpret_cast<float4*>(mb + (size_t)a * 8);
    float4 lo = make_float4(fmaxf(f[0], 0.f), fmaxf(f[1], 0.f), fmaxf(f[2], 0.f), fmaxf(f[3], 0.f));
    float4 hi = make_float4(fmaxf(f[4], 0.f), fmaxf(f[5], 0.f), fmaxf(f[6], 0.f), fmaxf(f[7], 0.f));
    dst[0] = lo; dst[1] = hi;
    if (k == 0) {
      int gp = (ty * 32 + y) * 256 + tx * 32 + x;
      a3b[gp] = make_uint4(a, adb[HW_ + gp], adb[2 * HW_ + gp], 0u);
    }
  }
}

// ---------------- conv2 + pool (proven 55 us version) ----------------
__global__ __launch_bounds__(256, 3) void c2p1(const float* __restrict__ mem, const float* __restrict__ w2,
                                               const float* __restrict__ b2, float* __restrict__ gPartial) {
  __shared__ float tile[98 * 68];
  __shared__ float w2s[1152];
  __shared__ float b2s[16];
  __shared__ float red[16][64];
  int blk = blockIdx.x; int sub = blk & 255; int b = blk >> 8;
  int r0 = sub * 96;
  int t = threadIdx.x;
  for (int idx = t; idx < 1152; idx += 256) w2s[idx] = w2[idx];
  if (t < 16) b2s[t] = b2[t];
  const float* mb = mem + (size_t)b * (N1 * 8);
  for (int q = t; q < 98 * 16; q += 256) {
    int ti = q >> 4, qw = q & 15;
    int r = r0 - 1 + ti;
    float4 v = make_float4(0.f, 0.f, 0.f, 0.f);
    if (r >= 0 && r < NROWS_) v = *reinterpret_cast<const float4*>(mb + (size_t)r * 64 + qw * 4);
    *reinterpret_cast<float4*>(&tile[ti * 68 + qw * 4]) = v;
  }
  __syncthreads();
  int co = t & 15, rowgrp = t >> 4;
  float wreg[3][3][8];
#pragma unroll
  for (int ci = 0; ci < 8; ++ci)
#pragma unroll
    for (int kr = 0; kr < 3; ++kr)
#pragma unroll
      for (int kc = 0; kc < 3; ++kc)
        wreg[kr][kc][ci] = w2s[(co * 8 + ci) * 9 + kr * 3 + kc];
  float bias = b2s[co];
  float pool[4] = {0.f, 0.f, 0.f, 0.f};
#define CSTEP(V, CI) do { \
    if (j < 3) { \
      if (li >= 1) s0[li - 1] = fmaf((V), wreg[j][2][CI], s0[li - 1]); \
      s0[li] = fmaf((V), wreg[j][1][CI], s0[li]); \
      if (li < 7) s0[li + 1] = fmaf((V), wreg[j][0][CI], s0[li + 1]); \
    } \
    if (j >= 1) { \
      if (li >= 1) s1[li - 1] = fmaf((V), wreg[j - 1][2][CI], s1[li - 1]); \
      s1[li] = fmaf((V), wreg[j - 1][1][CI], s1[li]); \
      if (li < 7) s1[li + 1] = fmaf((V), wreg[j - 1][0][CI], s1[li + 1]); \
    } \
  } while (0)
#pragma unroll 1
  for (int i = 0; i < 3; ++i) {
    int lr0 = rowgrp * 2 + 32 * i;
    float s0[8], s1[8];
#pragma unroll
    for (int l = 0; l < 8; ++l) { s0[l] = 0.f; s1[l] = 0.f; }
#pragma unroll
    for (int j = 0; j < 4; ++j) {
      const float* trow = &tile[(lr0 + j) * 68];
#pragma unroll
      for (int li = 0; li < 8; ++li) {
        float4 aa = *reinterpret_cast<const float4*>(trow + li * 8);
        float4 bb = *reinterpret_cast<const float4*>(trow + li * 8 + 4);
        CSTEP(aa.x, 0); CSTEP(aa.y, 1); CSTEP(aa.z, 2); CSTEP(aa.w, 3);
        CSTEP(bb.x, 4); CSTEP(bb.y, 5); CSTEP(bb.z, 6); CSTEP(bb.w, 7);
      }
    }
#pragma unroll
    for (int l = 0; l < 8; ++l)
      pool[l >> 1] += fmaxf(s0[l] + bias, 0.f) + fmaxf(s1[l] + bias, 0.f);
  }
#undef CSTEP
#pragma unroll
  for (int lb = 0; lb < 4; ++lb) red[rowgrp][lb * 16 + co] = pool[lb];
  __syncthreads();
  if (t < 64) {
    float s = 0.f;
#pragma unroll
    for (int rg = 0; rg < 16; ++rg) s += red[rg][t];
    int rb = sub >> 6, subW = sub & 63;
    gPartial[(((size_t)(b * 4 + rb) * 64 + subW) * 64) + t] = s;
  }
}

// deterministic stage-2 reduce -> flat [B][256]
__global__ void c2p2(const float* __restrict__ gPartial, float* __restrict__ flatS) {
  int b = blockIdx.x; int t = threadIdx.x;
  int ch = t >> 4; int rb = (t >> 2) & 3; int lb = t & 3;
  float s = 0.f;
  for (int sub = 0; sub < 64; ++sub)
    s += gPartial[(((size_t)(b * 4 + rb) * 64 + sub) * 64) + lb * 16 + ch];
  flatS[b * 256 + t] = s * (1.0f / 12288.0f);
}

// ---------------- projection GEMV fused with sort-2 key build ----------------
__global__ __launch_bounds__(256) void proj_k(const float* __restrict__ flatS, const float* __restrict__ pw,
                                              const float* __restrict__ pb, u64* __restrict__ kv2) {
  __shared__ float fs[8][256];
  int t = threadIdx.x;
  for (int i = t; i < 2048; i += 256) fs[i >> 8][i & 255] = flatS[i];
  __syncthreads();
  int q = t & 15; int og = t >> 4;
  int o = blockIdx.x * 16 + og;
  float acc[8];
#pragma unroll
  for (int b = 0; b < 8; ++b) acc[b] = 0.f;
  const float* wr = pw + (size_t)o * 256;
#pragma unroll
  for (int j = 0; j < 16; ++j) {
    float w = wr[q + 16 * j];
#pragma unroll
    for (int b = 0; b < 8; ++b) acc[b] = fmaf(fs[b][q + 16 * j], w, acc[b]);
  }
#pragma unroll
  for (int m = 1; m < 16; m <<= 1)
#pragma unroll
    for (int b = 0; b < 8; ++b) acc[b] += __shfl_xor(acc[b], m, 64);
  if (q == 0) {
    float bias = pb[o];
#pragma unroll
    for (int b = 0; b < 8; ++b) {
      u32 k = fkey(acc[b] + bias);
      kv2[(size_t)b * NOPS_ + o] = ((u64)k << 32) | (u32)o;
    }
  }
}

// ---------------- staged penalty + fused final reduce ----------------
__device__ __forceinline__ double stagedp(float d) {
  double h, base;
  if (d >= 0.f) { h = (double)d; base = h; }
  else { h = (double)(-d); base = h * h; }
  double f = (h <= 2.0) ? 1.0 : (h <= 4.0) ? 1.5 : (h <= 8.0) ? 2.0 : (h <= 16.0) ? 3.0 : 5.0;
  return base * f;
}

__global__ __launch_bounds__(256) void penalty_k(const u32* __restrict__ perm, const uint4* __restrict__ addr3,
                                                 double* __restrict__ partials, u32* __restrict__ ctr,
                                                 float* __restrict__ out) {
  int b = blockIdx.x >> 6; int blk = blockIdx.x & 63;
  int t = threadIdx.x, lane = t & 63;
  const u32* pm = perm + (size_t)b * NOPS_;
  const uint4* a3 = addr3 + (size_t)b * HW_;
  double intra = 0.0, inter = 0.0;
#pragma unroll
  for (int s = 0; s < 4; ++s) {
    int tg = blk * 1024 + s * 256 + t;
    u32 p = pm[tg];
    uint4 g = a3[p];
    float a0 = (float)g.x, a1 = (float)g.y, a2 = (float)g.z;
    intra += stagedp(a1 - a0) + stagedp(a2 - a1);
    float a2p = __shfl_up(a2, 1, 64);
    if (lane == 0 && tg > 0) {
      u32 pp = pm[tg - 1];
      a2p = (float)a3[pp].z;
    }
    if (tg > 0) inter += stagedp(a0 - a2p);
  }
#pragma unroll
  for (int m = 1; m < 64; m <<= 1) {
    intra += __shfl_xor(intra, m, 64);
    inter += __shfl_xor(inter, m, 64);
  }
  __shared__ double red[4][2];
  __shared__ u32 lastFlag;
  int wid = t >> 6;
  if (lane == 0) { red[wid][0] = inter; red[wid][1] = intra; }
  __syncthreads();
  if (t == 0) {
    double i0 = red[0][0] + red[1][0] + red[2][0] + red[3][0];
    double i1 = red[0][1] + red[1][1] + red[2][1] + red[3][1];
    partials[((size_t)b * 64 + blk) * 2 + 0] = i0;
    partials[((size_t)b * 64 + blk) * 2 + 1] = i1;
    __threadfence();
    u32 done = atomicAdd(ctr, 1u);
    lastFlag = (done == (u32)(BN * 64 - 1));
  }
  __syncthreads();
  if (lastFlag) {
    __threadfence();
    if (t < 16) {
      int which = t >> 3, bb = t & 7;
      double s = 0.0;
      for (int k = 0; k < 64; ++k) s += partials[((size_t)bb * 64 + k) * 2 + which];
      out[which * 8 + bb] = (float)s;
    }
  }
}

// ---------------- host ----------------
extern "C" void kernel_launch(void* const* d_in, const int* in_sizes, int n_in,
                              void* d_out, int out_size, void* d_ws, size_t ws_size,
                              hipStream_t stream) {
  const float* logits = (const float*)d_in[0];
  const float* w1 = (const float*)d_in[1];
  const float* b1 = (const float*)d_in[2];
  const float* w2 = (const float*)d_in[3];
  const float* b2 = (const float*)d_in[4];
  const float* pw = (const float*)d_in[5];
  const float* pb = (const float*)d_in[6];
  float* out = (float*)d_out;

  char* ws = (char*)d_ws;
  size_t o = 0;
  auto take = [&](size_t bytes) { char* p = ws + o; o += (bytes + 255) & ~(size_t)255; return p; };
  u64* kv1A = (u64*)take((size_t)BN * N1 * 8);
  u64* kv1B = (u64*)take((size_t)BN * N1 * 8);
  u64* kv2A = (u64*)take((size_t)BN * NOPS_ * 8);
  u64* kv2B = (u64*)take((size_t)BN * NOPS_ * 8);
  u32* addr = (u32*)take((size_t)BN * N1 * 4);
  float* mem = (float*)take((size_t)BN * N1 * 8 * 4);
  float* gPartial = (float*)take((size_t)BN * 4 * 64 * 64 * 4);
  float* flatS = (float*)take((size_t)BN * 256 * 4);
  u32* perm = (u32*)take((size_t)BN * NOPS_ * 4);
  double* partials = (double*)take((size_t)BN * 64 * 2 * 8);
  u32* lb2 = (u32*)take((size_t)4 * BN * NB2 * 256 * 4);     // 2.1 MB
  u32* gTotA = (u32*)take((size_t)2 * 4 * BN * 256 * 4);     // [sort][pass][b][256]
  u32* dBaseA = (u32*)take((size_t)2 * 4 * BN * 256 * 4);
  u32* ctrs = (u32*)take(64 * 4);
  uint4* addr3 = (uint4*)kv1A;            // alias: kv1A dead after sort-1 pass 2
  u32* lb1 = (u32*)mem;                   // alias: mem dead until conv1 (fully overwritten by it)

  const size_t LB1_BYTES = (size_t)4 * BN * NB1 * 256 * 4;   // 6.29 MB
  hipMemsetAsync(lb1, 0, LB1_BYTES, stream);
  hipMemsetAsync(lb2, 0, ((size_t)4 * BN * NB2 * 256 + 2 * 4 * BN * 256 * 2 + 64) * 4, stream);

  // ---- sort 1: OneSweep (totals once, then 4 lookback sweeps) ----
  histAll1<<<BN * 96, 256, 0, stream>>>(logits, gTotA);
  scanTot<<<32, 64, 0, stream>>>(gTotA, dBaseA);
  rs_sweep<true, false><<<BN * NB1, 256, 0, stream>>>(nullptr, logits, kv1B, nullptr,
      dBaseA + 0 * BN * 256, lb1 + (size_t)0 * BN * NB1 * 256, ctrs + 0, N1, NB1, 0);
  rs_sweep<false, false><<<BN * NB1, 256, 0, stream>>>(kv1B, nullptr, kv1A, nullptr,
      dBaseA + 1 * BN * 256, lb1 + (size_t)1 * BN * NB1 * 256, ctrs + 1, N1, NB1, 8);
  rs_sweep<false, false><<<BN * NB1, 256, 0, stream>>>(kv1A, nullptr, kv1B, nullptr,
      dBaseA + 2 * BN * 256, lb1 + (size_t)2 * BN * NB1 * 256, ctrs + 2, N1, NB1, 16);
  rs_sweep<false, true><<<BN * NB1, 256, 0, stream>>>(kv1B, nullptr, nullptr, addr,
      dBaseA + 3 * BN * 256, lb1 + (size_t)3 * BN * NB1 * 256, ctrs + 3, N1, NB1, 24);

  // conv1 + permutation scatter into mem (overwrites lb1 region); k==0 blocks build addr3
  conv1_scatter<<<BN * 3 * 64, 256, 0, stream>>>(addr, w1, b1, mem, addr3);

  // conv2 + adaptive pool
  c2p1<<<BN * 256, 256, 0, stream>>>(mem, w2, b2, gPartial);
  c2p2<<<BN, 256, 0, stream>>>(gPartial, flatS);

  // projection GEMV (+ sort-2 key build)
  proj_k<<<NOPS_ / 16, 256, 0, stream>>>(flatS, pw, pb, kv2A);

  // ---- sort 2: OneSweep ----
  histAll2<<<BN * NB2, 256, 0, stream>>>(kv2A, gTotA + 4 * BN * 256);
  scanTot<<<32, 64, 0, stream>>>(gTotA + 4 * BN * 256, dBaseA + 4 * BN * 256);
  rs_sweep<false, false><<<BN * NB2, 256, 0, stream>>>(kv2A, nullptr, kv2B, nullptr,
      dBaseA + 4 * BN * 256, lb2 + (size_t)0 * BN * NB2 * 256, ctrs + 4, NOPS_, NB2, 0);
  rs_sweep<false, false><<<BN * NB2, 256, 0, stream>>>(kv2B, nullptr, kv2A, nullptr,
      dBaseA + 5 * BN * 256, lb2 + (size_t)1 * BN * NB2 * 256, ctrs + 5, NOPS_, NB2, 8);
  rs_sweep<false, false><<<BN * NB2, 256, 0, stream>>>(kv2A, nullptr, kv2B, nullptr,
      dBaseA + 6 * BN * 256, lb2 + (size_t)2 * BN * NB2 * 256, ctrs + 6, NOPS_, NB2, 16);
  rs_sweep<false, true><<<BN * NB2, 256, 0, stream>>>(kv2B, nullptr, nullptr, perm,
      dBaseA + 7 * BN * 256, lb2 + (size_t)3 * BN * NB2 * 256, ctrs + 7, NOPS_, NB2, 24);

  // staged penalties + fused final reduce
  penalty_k<<<BN * 64, 256, 0, stream>>>(perm, addr3, partials, ctrs + 8, out);
}

// Round 10
// 356.731 us; speedup vs baseline: 1.0513x; 1.0513x over previous
//
#include <hip/hip_runtime.h>
#include <stdint.h>

typedef unsigned int u32;
typedef unsigned long long u64;

#define BN 8
#define HW_ 65536
#define N1 196608
#define NOPS_ 65536
#define NROWS_ 24576
#define NB1 192
#define NB2 64

// ---------------- sort key transform ----------------
__device__ __forceinline__ u32 fkey(float x) {
  u32 u = __float_as_uint(x);
  return u ^ ((u & 0x80000000u) ? 0xFFFFFFFFu : 0x80000000u);
}

// ---------------- radix pass: histogram (1024 items/block) + global digit totals ----------------
// non-FIRST reads only the HIGH DWORD of each u64 item (halves key-read bytes)
template <bool FIRST>
__global__ __launch_bounds__(256) void rs_hist(const u64* __restrict__ kv, const float* __restrict__ xf,
                                               u32* __restrict__ hist, u32* __restrict__ gTot,
                                               int n, int nblk, int shift) {
  __shared__ u32 h[256];
  int t = threadIdx.x;
  int b = blockIdx.x / nblk, blk = blockIdx.x % nblk;
  h[t] = 0;
  __syncthreads();
  if (FIRST) {
    const float* xp = xf + (size_t)b * n + (size_t)blk * 1024;
#pragma unroll
    for (int j = 0; j < 4; ++j) {
      u32 d = fkey(xp[j * 256 + t]) & 255u;
      atomicAdd(&h[d], 1u);
    }
  } else {
    const u32* kp32 = (const u32*)(kv + (size_t)b * n + (size_t)blk * 1024);
#pragma unroll
    for (int j = 0; j < 4; ++j) {
      u32 hi = kp32[2 * (j * 256 + t) + 1];
      u32 d = (hi >> shift) & 255u;
      atomicAdd(&h[d], 1u);
    }
  }
  __syncthreads();
  hist[((size_t)b * 256 + t) * nblk + blk] = h[t];
  atomicAdd(&gTot[b * 256 + t], h[t]);   // per-digit atomics: order-independent -> deterministic
}

// ---------------- wave-parallel scan helpers ----------------
__device__ __forceinline__ u32 wscan_incl(u32 x, int lane) {
#pragma unroll
  for (int off = 1; off < 64; off <<= 1) {
    u32 y = __shfl_up(x, off, 64);
    if (lane >= off) x += y;
  }
  return x;
}

// per-digit block-offset scan, with digit base folded in. grid = BN*64, 256 thr (wave = one digit)
__global__ __launch_bounds__(256) void rs_scanB(u32* __restrict__ hist, const u32* __restrict__ gTot, int nblk) {
  int t = threadIdx.x, w = t >> 6, lane = t & 63;
  int b = blockIdx.x >> 6, dgrp = blockIdx.x & 63;
  int d = dgrp * 4 + w;
  const u32* gt = gTot + b * 256;
  u32 base = 0, run = 0;
  int dc = d >> 6, dl = d & 63;
#pragma unroll
  for (int c = 0; c < 4; ++c) {
    u32 v = gt[c * 64 + lane];
    u32 incl = wscan_incl(v, lane);
    if (c == dc) base = run + __shfl(incl - v, dl, 64);
    run += __shfl(incl, 63, 64);
  }
  u32* p = hist + ((size_t)b * 256 + d) * nblk;
  u32 acc = base;
  for (int c = 0; c < nblk; c += 64) {
    u32 v = p[c + lane];
    u32 incl = wscan_incl(v, lane);
    p[c + lane] = acc + incl - v;
    acc += __shfl(incl, 63, 64);
  }
}

// ---------------- stable scatter v5: LDS-staged digit-sorted writes (coalesced) ----------------
template <bool FIRST, bool FINAL>
__global__ __launch_bounds__(256) void rs_scatter(const u64* __restrict__ kvIn, const float* __restrict__ xf,
                                                  u64* __restrict__ out64, u32* __restrict__ out32,
                                                  const u32* __restrict__ hist, int n, int nblk, int shift) {
  __shared__ u32 sBase[256];
  __shared__ u32 cnt[16][256];   // [strip*4+wave][digit]
  __shared__ u32 dpre[256];      // block-local exclusive digit prefix
  __shared__ u32 wsum[4];
  __shared__ u64 stage[1024];
  int t = threadIdx.x, lane = t & 63, wid = t >> 6;
  int b = blockIdx.x / nblk, blk = blockIdx.x % nblk;
  u64 kvr[4]; u32 dg[4];
  if (FIRST) {
    const float* xp = xf + (size_t)b * n + (size_t)blk * 1024;
#pragma unroll
    for (int j = 0; j < 4; ++j) {
      u32 k = fkey(xp[j * 256 + t]);
      kvr[j] = ((u64)k << 32) | (u32)(blk * 1024 + j * 256 + t);
      dg[j] = k & 255u;
    }
  } else {
    const u64* kp = kvIn + (size_t)b * n + (size_t)blk * 1024;
#pragma unroll
    for (int j = 0; j < 4; ++j) {
      kvr[j] = kp[j * 256 + t];
      dg[j] = (u32)(kvr[j] >> (32 + shift)) & 255u;
    }
  }
  sBase[t] = hist[((size_t)b * 256 + t) * nblk + blk];
#pragma unroll
  for (int r = 0; r < 16; ++r) cnt[r][t] = 0;
  __syncthreads();
  u64 lmask = (1ull << lane) - 1ull;
  u32 rw[4];
#pragma unroll
  for (int j = 0; j < 4; ++j) {
    u32 d = dg[j];
    u64 peers = ~0ull;
#pragma unroll
    for (int bit = 0; bit < 8; ++bit) {
      u64 bal = __ballot((d >> bit) & 1);
      peers &= ((d >> bit) & 1) ? bal : ~bal;
    }
    u64 lower = peers & lmask;
    rw[j] = (u32)__popcll(lower);
    if (lower == 0) cnt[j * 4 + wid][d] = (u32)__popcll(peers);
  }
  __syncthreads();
  // thread t owns digit t: local prefix in item order (strip, wave) -> stability
  u32 run = 0;
#pragma unroll
  for (int r = 0; r < 16; ++r) { u32 c = cnt[r][t]; cnt[r][t] = run; run += c; }
  // block-wide exclusive digit prefix
  u32 incl = wscan_incl(run, lane);
  if (lane == 63) wsum[wid] = incl;
  __syncthreads();
  u32 woff = 0;
#pragma unroll
  for (int w = 0; w < 4; ++w) if (w < wid) woff += wsum[w];
  dpre[t] = woff + incl - run;
  __syncthreads();
  // stage into LDS in digit-sorted (final) order
#pragma unroll
  for (int j = 0; j < 4; ++j) {
    u32 d = dg[j];
    u32 lpos = dpre[d] + cnt[j * 4 + wid][d] + rw[j];
    stage[lpos] = kvr[j];
  }
  __syncthreads();
  // coalesced write-out
#pragma unroll
  for (int s = 0; s < 4; ++s) {
    int i = s * 256 + t;
    u64 kv = stage[i];
    u32 d = (u32)(kv >> (32 + shift)) & 255u;
    u32 g = sBase[d] + ((u32)i - dpre[d]);
    if (FINAL) out32[(size_t)b * n + g] = (u32)kv;
    else out64[(size_t)b * n + g] = kv;
  }
}

// ---------------- conv1 (grouped 1->8, 3x3 SAME) + permutation scatter + addr3 build (k==0) ----------------
__global__ __launch_bounds__(256) void conv1_scatter(const u32* __restrict__ addr, const float* __restrict__ w1,
                                                     const float* __restrict__ b1, float* __restrict__ mem,
                                                     uint4* __restrict__ addr3) {
  __shared__ float ax[34][34];
  __shared__ float ws[8][9];
  __shared__ float bs[8];
  int t = threadIdx.x;
  int blk = blockIdx.x;
  int tile = blk & 63; int bk2 = blk >> 6; int k = bk2 % 3; int b = bk2 / 3;
  int ty = tile >> 3, tx = tile & 7;
  if (t < 72) ws[t / 9][t % 9] = w1[k * 72 + t];
  if (t >= 128 && t < 136) bs[t - 128] = b1[k * 8 + (t - 128)];
  const u32* ap = addr + (size_t)b * N1 + (size_t)k * HW_;
  for (int idx = t; idx < 34 * 34; idx += 256) {
    int y = idx / 34, x = idx % 34;
    int h = ty * 32 + y - 1, w = tx * 32 + x - 1;
    float v = 0.f;
    if (h >= 0 && h < 256 && w >= 0 && w < 256) v = (float)ap[h * 256 + w];
    ax[y][x] = v;
  }
  __syncthreads();
  float* mb = mem + (size_t)b * N1 * 8;
  const u32* adb = addr + (size_t)b * N1;
  uint4* a3b = addr3 + (size_t)b * HW_;
#pragma unroll
  for (int s = 0; s < 4; ++s) {
    int p = t + s * 256;
    int y = p >> 5, x = p & 31;
    float f[8];
#pragma unroll
    for (int c = 0; c < 8; ++c) f[c] = bs[c];
#pragma unroll
    for (int dy = 0; dy < 3; ++dy)
#pragma unroll
      for (int dx = 0; dx < 3; ++dx) {
        float v = ax[y + dy][x + dx];
#pragma unroll
        for (int c = 0; c < 8; ++c) f[c] = fmaf(ws[c][dy * 3 + dx], v, f[c]);
      }
    u32 a = (u32)ax[y + 1][x + 1];
    float4* dst = reinterpret_cast<float4*>(mb + (size_t)a * 8);
    float4 lo = make_float4(fmaxf(f[0], 0.f), fmaxf(f[1], 0.f), fmaxf(f[2], 0.f), fmaxf(f[3], 0.f));
    float4 hi = make_float4(fmaxf(f[4], 0.f), fmaxf(f[5], 0.f), fmaxf(f[6], 0.f), fmaxf(f[7], 0.f));
    dst[0] = lo; dst[1] = hi;
    if (k == 0) {
      int gp = (ty * 32 + y) * 256 + tx * 32 + x;
      a3b[gp] = make_uint4(a, adb[HW_ + gp], adb[2 * HW_ + gp], 0u);
    }
  }
}

// ---------------- conv2 + pool (proven 55 us) + fused stage-2 reduce (last-block) ----------------
__global__ __launch_bounds__(256, 3) void c2p1(const float* __restrict__ mem, const float* __restrict__ w2,
                                               const float* __restrict__ b2, float* __restrict__ gPartial,
                                               u32* __restrict__ ctr, float* __restrict__ flatS) {
  __shared__ float tile[98 * 68];
  __shared__ float w2s[1152];
  __shared__ float b2s[16];
  __shared__ float red[16][64];
  __shared__ u32 lastFlag;
  int blk = blockIdx.x; int sub = blk & 255; int b = blk >> 8;
  int r0 = sub * 96;
  int t = threadIdx.x;
  for (int idx = t; idx < 1152; idx += 256) w2s[idx] = w2[idx];
  if (t < 16) b2s[t] = b2[t];
  const float* mb = mem + (size_t)b * (N1 * 8);
  for (int q = t; q < 98 * 16; q += 256) {
    int ti = q >> 4, qw = q & 15;
    int r = r0 - 1 + ti;
    float4 v = make_float4(0.f, 0.f, 0.f, 0.f);
    if (r >= 0 && r < NROWS_) v = *reinterpret_cast<const float4*>(mb + (size_t)r * 64 + qw * 4);
    *reinterpret_cast<float4*>(&tile[ti * 68 + qw * 4]) = v;
  }
  __syncthreads();
  int co = t & 15, rowgrp = t >> 4;
  float wreg[3][3][8];
#pragma unroll
  for (int ci = 0; ci < 8; ++ci)
#pragma unroll
    for (int kr = 0; kr < 3; ++kr)
#pragma unroll
      for (int kc = 0; kc < 3; ++kc)
        wreg[kr][kc][ci] = w2s[(co * 8 + ci) * 9 + kr * 3 + kc];
  float bias = b2s[co];
  float pool[4] = {0.f, 0.f, 0.f, 0.f};
#define CSTEP(V, CI) do { \
    if (j < 3) { \
      if (li >= 1) s0[li - 1] = fmaf((V), wreg[j][2][CI], s0[li - 1]); \
      s0[li] = fmaf((V), wreg[j][1][CI], s0[li]); \
      if (li < 7) s0[li + 1] = fmaf((V), wreg[j][0][CI], s0[li + 1]); \
    } \
    if (j >= 1) { \
      if (li >= 1) s1[li - 1] = fmaf((V), wreg[j - 1][2][CI], s1[li - 1]); \
      s1[li] = fmaf((V), wreg[j - 1][1][CI], s1[li]); \
      if (li < 7) s1[li + 1] = fmaf((V), wreg[j - 1][0][CI], s1[li + 1]); \
    } \
  } while (0)
#pragma unroll 1
  for (int i = 0; i < 3; ++i) {
    int lr0 = rowgrp * 2 + 32 * i;
    float s0[8], s1[8];
#pragma unroll
    for (int l = 0; l < 8; ++l) { s0[l] = 0.f; s1[l] = 0.f; }
#pragma unroll
    for (int j = 0; j < 4; ++j) {
      const float* trow = &tile[(lr0 + j) * 68];
#pragma unroll
      for (int li = 0; li < 8; ++li) {
        float4 aa = *reinterpret_cast<const float4*>(trow + li * 8);
        float4 bb = *reinterpret_cast<const float4*>(trow + li * 8 + 4);
        CSTEP(aa.x, 0); CSTEP(aa.y, 1); CSTEP(aa.z, 2); CSTEP(aa.w, 3);
        CSTEP(bb.x, 4); CSTEP(bb.y, 5); CSTEP(bb.z, 6); CSTEP(bb.w, 7);
      }
    }
#pragma unroll
    for (int l = 0; l < 8; ++l)
      pool[l >> 1] += fmaxf(s0[l] + bias, 0.f) + fmaxf(s1[l] + bias, 0.f);
  }
#undef CSTEP
#pragma unroll
  for (int lb = 0; lb < 4; ++lb) red[rowgrp][lb * 16 + co] = pool[lb];
  __syncthreads();
  if (t < 64) {
    float s = 0.f;
#pragma unroll
    for (int rg = 0; rg < 16; ++rg) s += red[rg][t];
    int rb = sub >> 6, subW = sub & 63;
    gPartial[(((size_t)(b * 4 + rb) * 64 + subW) * 64) + t] = s;
  }
  // fused stage-2 reduce: exactly one (the last) block; fixed order -> deterministic
  __syncthreads();
  if (t == 0) {
    __threadfence();
    u32 done = atomicAdd(ctr, 1u);
    lastFlag = (done == (u32)(BN * 256 - 1));
  }
  __syncthreads();
  if (lastFlag) {
    __threadfence();
    for (int i = t; i < BN * 256; i += 256) {
      int bb = i >> 8, tt = i & 255;
      int ch = tt >> 4, rb = (tt >> 2) & 3, lb = tt & 3;
      float s = 0.f;
      for (int sub2 = 0; sub2 < 64; ++sub2)
        s += gPartial[(((size_t)(bb * 4 + rb) * 64 + sub2) * 64) + lb * 16 + ch];
      flatS[bb * 256 + tt] = s * (1.0f / 12288.0f);
    }
  }
}

// ---------------- projection GEMV fused with sort-2 key build ----------------
__global__ __launch_bounds__(256) void proj_k(const float* __restrict__ flatS, const float* __restrict__ pw,
                                              const float* __restrict__ pb, u64* __restrict__ kv2) {
  __shared__ float fs[8][256];
  int t = threadIdx.x;
  for (int i = t; i < 2048; i += 256) fs[i >> 8][i & 255] = flatS[i];
  __syncthreads();
  int q = t & 15; int og = t >> 4;
  int o = blockIdx.x * 16 + og;
  float acc[8];
#pragma unroll
  for (int b = 0; b < 8; ++b) acc[b] = 0.f;
  const float* wr = pw + (size_t)o * 256;
#pragma unroll
  for (int j = 0; j < 16; ++j) {
    float w = wr[q + 16 * j];
#pragma unroll
    for (int b = 0; b < 8; ++b) acc[b] = fmaf(fs[b][q + 16 * j], w, acc[b]);
  }
#pragma unroll
  for (int m = 1; m < 16; m <<= 1)
#pragma unroll
    for (int b = 0; b < 8; ++b) acc[b] += __shfl_xor(acc[b], m, 64);
  if (q == 0) {
    float bias = pb[o];
#pragma unroll
    for (int b = 0; b < 8; ++b) {
      u32 k = fkey(acc[b] + bias);
      kv2[(size_t)b * NOPS_ + o] = ((u64)k << 32) | (u32)o;
    }
  }
}

// ---------------- staged penalty + fused final reduce ----------------
__device__ __forceinline__ double stagedp(float d) {
  double h, base;
  if (d >= 0.f) { h = (double)d; base = h; }
  else { h = (double)(-d); base = h * h; }
  double f = (h <= 2.0) ? 1.0 : (h <= 4.0) ? 1.5 : (h <= 8.0) ? 2.0 : (h <= 16.0) ? 3.0 : 5.0;
  return base * f;
}

__global__ __launch_bounds__(256) void penalty_k(const u32* __restrict__ perm, const uint4* __restrict__ addr3,
                                                 double* __restrict__ partials, u32* __restrict__ ctr,
                                                 float* __restrict__ out) {
  int b = blockIdx.x >> 6; int blk = blockIdx.x & 63;
  int t = threadIdx.x, lane = t & 63;
  const u32* pm = perm + (size_t)b * NOPS_;
  const uint4* a3 = addr3 + (size_t)b * HW_;
  double intra = 0.0, inter = 0.0;
#pragma unroll
  for (int s = 0; s < 4; ++s) {
    int tg = blk * 1024 + s * 256 + t;
    u32 p = pm[tg];
    uint4 g = a3[p];
    float a0 = (float)g.x, a1 = (float)g.y, a2 = (float)g.z;
    intra += stagedp(a1 - a0) + stagedp(a2 - a1);
    float a2p = __shfl_up(a2, 1, 64);
    if (lane == 0 && tg > 0) {
      u32 pp = pm[tg - 1];
      a2p = (float)a3[pp].z;
    }
    if (tg > 0) inter += stagedp(a0 - a2p);
  }
#pragma unroll
  for (int m = 1; m < 64; m <<= 1) {
    intra += __shfl_xor(intra, m, 64);
    inter += __shfl_xor(inter, m, 64);
  }
  __shared__ double red[4][2];
  __shared__ u32 lastFlag;
  int wid = t >> 6;
  if (lane == 0) { red[wid][0] = inter; red[wid][1] = intra; }
  __syncthreads();
  if (t == 0) {
    double i0 = red[0][0] + red[1][0] + red[2][0] + red[3][0];
    double i1 = red[0][1] + red[1][1] + red[2][1] + red[3][1];
    partials[((size_t)b * 64 + blk) * 2 + 0] = i0;
    partials[((size_t)b * 64 + blk) * 2 + 1] = i1;
    __threadfence();
    u32 done = atomicAdd(ctr, 1u);
    lastFlag = (done == (u32)(BN * 64 - 1));
  }
  __syncthreads();
  if (lastFlag) {
    __threadfence();
    if (t < 16) {
      int which = t >> 3, bb = t & 7;
      double s = 0.0;
      for (int k = 0; k < 64; ++k) s += partials[((size_t)bb * 64 + k) * 2 + which];
      out[which * 8 + bb] = (float)s;
    }
  }
}

// ---------------- host ----------------
extern "C" void kernel_launch(void* const* d_in, const int* in_sizes, int n_in,
                              void* d_out, int out_size, void* d_ws, size_t ws_size,
                              hipStream_t stream) {
  const float* logits = (const float*)d_in[0];
  const float* w1 = (const float*)d_in[1];
  const float* b1 = (const float*)d_in[2];
  const float* w2 = (const float*)d_in[3];
  const float* b2 = (const float*)d_in[4];
  const float* pw = (const float*)d_in[5];
  const float* pb = (const float*)d_in[6];
  float* out = (float*)d_out;

  char* ws = (char*)d_ws;
  size_t o = 0;
  auto take = [&](size_t bytes) { char* p = ws + o; o += (bytes + 255) & ~(size_t)255; return p; };
  u64* kv1A = (u64*)take((size_t)BN * N1 * 8);
  u64* kv1B = (u64*)take((size_t)BN * N1 * 8);
  u64* kv2A = (u64*)take((size_t)BN * NOPS_ * 8);
  u64* kv2B = (u64*)take((size_t)BN * NOPS_ * 8);
  u32* hist = (u32*)take((size_t)256 * NB1 * BN * 4);
  u32* gTotAll = (u32*)take(((size_t)8 * BN * 256 + 64) * 4);   // + ctr slots
  u32* addr = (u32*)take((size_t)BN * N1 * 4);
  float* mem = (float*)take((size_t)BN * N1 * 8 * 4);
  float* gPartial = (float*)take((size_t)BN * 4 * 64 * 64 * 4);
  float* flatS = (float*)take((size_t)BN * 256 * 4);
  u32* perm = (u32*)take((size_t)BN * NOPS_ * 4);
  double* partials = (double*)take((size_t)BN * 64 * 2 * 8);
  uint4* addr3 = (uint4*)kv1A;                  // alias: kv1A dead after sort-1 pass 2
  u32* ctr = gTotAll + (size_t)8 * BN * 256;    // [0]=penalty, [1]=c2p1; zeroed by memset

  hipMemsetAsync(gTotAll, 0, ((size_t)8 * BN * 256 + 64) * 4, stream);

  // sort 1: stable argsort of mem_logits (pass 0 builds keys from logits on the fly)
  {
    u32* gT = gTotAll;
    rs_hist<true><<<BN * NB1, 256, 0, stream>>>(nullptr, logits, hist, gT, N1, NB1, 0);
    rs_scanB<<<BN * 64, 256, 0, stream>>>(hist, gT, NB1);
    rs_scatter<true, false><<<BN * NB1, 256, 0, stream>>>(nullptr, logits, kv1B, nullptr, hist, N1, NB1, 0);
  }
  u64* src = kv1B; u64* dst = kv1A;
  for (int p = 1; p < 4; ++p) {
    u32* gT = gTotAll + (size_t)p * BN * 256;
    rs_hist<false><<<BN * NB1, 256, 0, stream>>>(src, nullptr, hist, gT, N1, NB1, p * 8);
    rs_scanB<<<BN * 64, 256, 0, stream>>>(hist, gT, NB1);
    if (p < 3) {
      rs_scatter<false, false><<<BN * NB1, 256, 0, stream>>>(src, nullptr, dst, nullptr, hist, N1, NB1, p * 8);
      u64* tmp = src; src = dst; dst = tmp;
    } else {
      rs_scatter<false, true><<<BN * NB1, 256, 0, stream>>>(src, nullptr, nullptr, addr, hist, N1, NB1, p * 8);
    }
  }

  // conv1 + permutation scatter into mem [B][N1][8]; k==0 blocks also build addr3
  conv1_scatter<<<BN * 3 * 64, 256, 0, stream>>>(addr, w1, b1, mem, addr3);

  // conv2 + adaptive pool (stage-2 reduce fused via last-block)
  c2p1<<<BN * 256, 256, 0, stream>>>(mem, w2, b2, gPartial, ctr + 1, flatS);

  // projection GEMV (+ sort-2 key build)
  proj_k<<<NOPS_ / 16, 256, 0, stream>>>(flatS, pw, pb, kv2A);

  // sort 2: stable argsort of op_logits
  src = kv2A; dst = kv2B;
  for (int p = 0; p < 4; ++p) {
    u32* gT = gTotAll + (size_t)(4 + p) * BN * 256;
    rs_hist<false><<<BN * NB2, 256, 0, stream>>>(src, nullptr, hist, gT, NOPS_, NB2, p * 8);
    rs_scanB<<<BN * 64, 256, 0, stream>>>(hist, gT, NB2);
    if (p < 3) {
      rs_scatter<false, false><<<BN * NB2, 256, 0, stream>>>(src, nullptr, dst, nullptr, hist, NOPS_, NB2, p * 8);
      u64* tmp = src; src = dst; dst = tmp;
    } else {
      rs_scatter<false, true><<<BN * NB2, 256, 0, stream>>>(src, nullptr, nullptr, perm, hist, NOPS_, NB2, p * 8);
    }
  }

  // staged penalties + fused final reduce (last-block pattern)
  penalty_k<<<BN * 64, 256, 0, stream>>>(perm, addr3, partials, ctr, out);
}

// Round 11
// 289.386 us; speedup vs baseline: 1.2959x; 1.2327x over previous
//
#include <hip/hip_runtime.h>
#include <stdint.h>

typedef unsigned int u32;
typedef unsigned long long u64;

#define BN 8
#define HW_ 65536
#define N1 196608
#define NOPS_ 65536
#define NROWS_ 24576
#define NB1 192
#define NB2 64

// ---------------- sort key transform ----------------
__device__ __forceinline__ u32 fkey(float x) {
  u32 u = __float_as_uint(x);
  return u ^ ((u & 0x80000000u) ? 0xFFFFFFFFu : 0x80000000u);
}

// ---------------- radix pass: histogram (1024 items/block) + global digit totals ----------------
// non-FIRST reads only the HIGH DWORD of each u64 item (halves key-read bytes)
template <bool FIRST>
__global__ __launch_bounds__(256) void rs_hist(const u64* __restrict__ kv, const float* __restrict__ xf,
                                               u32* __restrict__ hist, u32* __restrict__ gTot,
                                               int n, int nblk, int shift) {
  __shared__ u32 h[256];
  int t = threadIdx.x;
  int b = blockIdx.x / nblk, blk = blockIdx.x % nblk;
  h[t] = 0;
  __syncthreads();
  if (FIRST) {
    const float* xp = xf + (size_t)b * n + (size_t)blk * 1024;
#pragma unroll
    for (int j = 0; j < 4; ++j) {
      u32 d = fkey(xp[j * 256 + t]) & 255u;
      atomicAdd(&h[d], 1u);
    }
  } else {
    const u32* kp32 = (const u32*)(kv + (size_t)b * n + (size_t)blk * 1024);
#pragma unroll
    for (int j = 0; j < 4; ++j) {
      u32 hi = kp32[2 * (j * 256 + t) + 1];
      u32 d = (hi >> shift) & 255u;
      atomicAdd(&h[d], 1u);
    }
  }
  __syncthreads();
  hist[((size_t)b * 256 + t) * nblk + blk] = h[t];
  atomicAdd(&gTot[b * 256 + t], h[t]);   // per-digit atomics: order-independent -> deterministic
}

// ---------------- wave-parallel scan helpers ----------------
__device__ __forceinline__ u32 wscan_incl(u32 x, int lane) {
#pragma unroll
  for (int off = 1; off < 64; off <<= 1) {
    u32 y = __shfl_up(x, off, 64);
    if (lane >= off) x += y;
  }
  return x;
}

// per-digit block-offset scan, with digit base folded in. grid = BN*64, 256 thr (wave = one digit)
__global__ __launch_bounds__(256) void rs_scanB(u32* __restrict__ hist, const u32* __restrict__ gTot, int nblk) {
  int t = threadIdx.x, w = t >> 6, lane = t & 63;
  int b = blockIdx.x >> 6, dgrp = blockIdx.x & 63;
  int d = dgrp * 4 + w;
  const u32* gt = gTot + b * 256;
  u32 base = 0, run = 0;
  int dc = d >> 6, dl = d & 63;
#pragma unroll
  for (int c = 0; c < 4; ++c) {
    u32 v = gt[c * 64 + lane];
    u32 incl = wscan_incl(v, lane);
    if (c == dc) base = run + __shfl(incl - v, dl, 64);
    run += __shfl(incl, 63, 64);
  }
  u32* p = hist + ((size_t)b * 256 + d) * nblk;
  u32 acc = base;
  for (int c = 0; c < nblk; c += 64) {
    u32 v = p[c + lane];
    u32 incl = wscan_incl(v, lane);
    p[c + lane] = acc + incl - v;
    acc += __shfl(incl, 63, 64);
  }
}

// ---------------- stable scatter v5: LDS-staged digit-sorted writes (coalesced) ----------------
template <bool FIRST, bool FINAL>
__global__ __launch_bounds__(256) void rs_scatter(const u64* __restrict__ kvIn, const float* __restrict__ xf,
                                                  u64* __restrict__ out64, u32* __restrict__ out32,
                                                  const u32* __restrict__ hist, int n, int nblk, int shift) {
  __shared__ u32 sBase[256];
  __shared__ u32 cnt[16][256];   // [strip*4+wave][digit]
  __shared__ u32 dpre[256];      // block-local exclusive digit prefix
  __shared__ u32 wsum[4];
  __shared__ u64 stage[1024];
  int t = threadIdx.x, lane = t & 63, wid = t >> 6;
  int b = blockIdx.x / nblk, blk = blockIdx.x % nblk;
  u64 kvr[4]; u32 dg[4];
  if (FIRST) {
    const float* xp = xf + (size_t)b * n + (size_t)blk * 1024;
#pragma unroll
    for (int j = 0; j < 4; ++j) {
      u32 k = fkey(xp[j * 256 + t]);
      kvr[j] = ((u64)k << 32) | (u32)(blk * 1024 + j * 256 + t);
      dg[j] = k & 255u;
    }
  } else {
    const u64* kp = kvIn + (size_t)b * n + (size_t)blk * 1024;
#pragma unroll
    for (int j = 0; j < 4; ++j) {
      kvr[j] = kp[j * 256 + t];
      dg[j] = (u32)(kvr[j] >> (32 + shift)) & 255u;
    }
  }
  sBase[t] = hist[((size_t)b * 256 + t) * nblk + blk];
#pragma unroll
  for (int r = 0; r < 16; ++r) cnt[r][t] = 0;
  __syncthreads();
  u64 lmask = (1ull << lane) - 1ull;
  u32 rw[4];
#pragma unroll
  for (int j = 0; j < 4; ++j) {
    u32 d = dg[j];
    u64 peers = ~0ull;
#pragma unroll
    for (int bit = 0; bit < 8; ++bit) {
      u64 bal = __ballot((d >> bit) & 1);
      peers &= ((d >> bit) & 1) ? bal : ~bal;
    }
    u64 lower = peers & lmask;
    rw[j] = (u32)__popcll(lower);
    if (lower == 0) cnt[j * 4 + wid][d] = (u32)__popcll(peers);
  }
  __syncthreads();
  // thread t owns digit t: local prefix in item order (strip, wave) -> stability
  u32 run = 0;
#pragma unroll
  for (int r = 0; r < 16; ++r) { u32 c = cnt[r][t]; cnt[r][t] = run; run += c; }
  // block-wide exclusive digit prefix
  u32 incl = wscan_incl(run, lane);
  if (lane == 63) wsum[wid] = incl;
  __syncthreads();
  u32 woff = 0;
#pragma unroll
  for (int w = 0; w < 4; ++w) if (w < wid) woff += wsum[w];
  dpre[t] = woff + incl - run;
  __syncthreads();
  // stage into LDS in digit-sorted (final) order
#pragma unroll
  for (int j = 0; j < 4; ++j) {
    u32 d = dg[j];
    u32 lpos = dpre[d] + cnt[j * 4 + wid][d] + rw[j];
    stage[lpos] = kvr[j];
  }
  __syncthreads();
  // coalesced write-out
#pragma unroll
  for (int s = 0; s < 4; ++s) {
    int i = s * 256 + t;
    u64 kv = stage[i];
    u32 d = (u32)(kv >> (32 + shift)) & 255u;
    u32 g = sBase[d] + ((u32)i - dpre[d]);
    if (FINAL) out32[(size_t)b * n + g] = (u32)kv;
    else out64[(size_t)b * n + g] = kv;
  }
}

// ---------------- conv1 (grouped 1->8, 3x3 SAME) + permutation scatter + addr3 build (k==0) ----------------
__global__ __launch_bounds__(256) void conv1_scatter(const u32* __restrict__ addr, const float* __restrict__ w1,
                                                     const float* __restrict__ b1, float* __restrict__ mem,
                                                     uint4* __restrict__ addr3) {
  __shared__ float ax[34][34];
  __shared__ float ws[8][9];
  __shared__ float bs[8];
  int t = threadIdx.x;
  int blk = blockIdx.x;
  int tile = blk & 63; int bk2 = blk >> 6; int k = bk2 % 3; int b = bk2 / 3;
  int ty = tile >> 3, tx = tile & 7;
  if (t < 72) ws[t / 9][t % 9] = w1[k * 72 + t];
  if (t >= 128 && t < 136) bs[t - 128] = b1[k * 8 + (t - 128)];
  const u32* ap = addr + (size_t)b * N1 + (size_t)k * HW_;
  for (int idx = t; idx < 34 * 34; idx += 256) {
    int y = idx / 34, x = idx % 34;
    int h = ty * 32 + y - 1, w = tx * 32 + x - 1;
    float v = 0.f;
    if (h >= 0 && h < 256 && w >= 0 && w < 256) v = (float)ap[h * 256 + w];
    ax[y][x] = v;
  }
  __syncthreads();
  float* mb = mem + (size_t)b * N1 * 8;
  const u32* adb = addr + (size_t)b * N1;
  uint4* a3b = addr3 + (size_t)b * HW_;
#pragma unroll
  for (int s = 0; s < 4; ++s) {
    int p = t + s * 256;
    int y = p >> 5, x = p & 31;
    float f[8];
#pragma unroll
    for (int c = 0; c < 8; ++c) f[c] = bs[c];
#pragma unroll
    for (int dy = 0; dy < 3; ++dy)
#pragma unroll
      for (int dx = 0; dx < 3; ++dx) {
        float v = ax[y + dy][x + dx];
#pragma unroll
        for (int c = 0; c < 8; ++c) f[c] = fmaf(ws[c][dy * 3 + dx], v, f[c]);
      }
    u32 a = (u32)ax[y + 1][x + 1];
    float4* dst = reinterpret_cast<float4*>(mb + (size_t)a * 8);
    float4 lo = make_float4(fmaxf(f[0], 0.f), fmaxf(f[1], 0.f), fmaxf(f[2], 0.f), fmaxf(f[3], 0.f));
    float4 hi = make_float4(fmaxf(f[4], 0.f), fmaxf(f[5], 0.f), fmaxf(f[6], 0.f), fmaxf(f[7], 0.f));
    dst[0] = lo; dst[1] = hi;
    if (k == 0) {
      int gp = (ty * 32 + y) * 256 + tx * 32 + x;
      a3b[gp] = make_uint4(a, adb[HW_ + gp], adb[2 * HW_ + gp], 0u);
    }
  }
}

// ---------------- conv2 + pool (proven 55 us version, no fusion) ----------------
__global__ __launch_bounds__(256, 3) void c2p1(const float* __restrict__ mem, const float* __restrict__ w2,
                                               const float* __restrict__ b2, float* __restrict__ gPartial) {
  __shared__ float tile[98 * 68];
  __shared__ float w2s[1152];
  __shared__ float b2s[16];
  __shared__ float red[16][64];
  int blk = blockIdx.x; int sub = blk & 255; int b = blk >> 8;
  int r0 = sub * 96;
  int t = threadIdx.x;
  for (int idx = t; idx < 1152; idx += 256) w2s[idx] = w2[idx];
  if (t < 16) b2s[t] = b2[t];
  const float* mb = mem + (size_t)b * (N1 * 8);
  for (int q = t; q < 98 * 16; q += 256) {
    int ti = q >> 4, qw = q & 15;
    int r = r0 - 1 + ti;
    float4 v = make_float4(0.f, 0.f, 0.f, 0.f);
    if (r >= 0 && r < NROWS_) v = *reinterpret_cast<const float4*>(mb + (size_t)r * 64 + qw * 4);
    *reinterpret_cast<float4*>(&tile[ti * 68 + qw * 4]) = v;
  }
  __syncthreads();
  int co = t & 15, rowgrp = t >> 4;
  float wreg[3][3][8];
#pragma unroll
  for (int ci = 0; ci < 8; ++ci)
#pragma unroll
    for (int kr = 0; kr < 3; ++kr)
#pragma unroll
      for (int kc = 0; kc < 3; ++kc)
        wreg[kr][kc][ci] = w2s[(co * 8 + ci) * 9 + kr * 3 + kc];
  float bias = b2s[co];
  float pool[4] = {0.f, 0.f, 0.f, 0.f};
#define CSTEP(V, CI) do { \
    if (j < 3) { \
      if (li >= 1) s0[li - 1] = fmaf((V), wreg[j][2][CI], s0[li - 1]); \
      s0[li] = fmaf((V), wreg[j][1][CI], s0[li]); \
      if (li < 7) s0[li + 1] = fmaf((V), wreg[j][0][CI], s0[li + 1]); \
    } \
    if (j >= 1) { \
      if (li >= 1) s1[li - 1] = fmaf((V), wreg[j - 1][2][CI], s1[li - 1]); \
      s1[li] = fmaf((V), wreg[j - 1][1][CI], s1[li]); \
      if (li < 7) s1[li + 1] = fmaf((V), wreg[j - 1][0][CI], s1[li + 1]); \
    } \
  } while (0)
#pragma unroll 1
  for (int i = 0; i < 3; ++i) {
    int lr0 = rowgrp * 2 + 32 * i;
    float s0[8], s1[8];
#pragma unroll
    for (int l = 0; l < 8; ++l) { s0[l] = 0.f; s1[l] = 0.f; }
#pragma unroll
    for (int j = 0; j < 4; ++j) {
      const float* trow = &tile[(lr0 + j) * 68];
#pragma unroll
      for (int li = 0; li < 8; ++li) {
        float4 aa = *reinterpret_cast<const float4*>(trow + li * 8);
        float4 bb = *reinterpret_cast<const float4*>(trow + li * 8 + 4);
        CSTEP(aa.x, 0); CSTEP(aa.y, 1); CSTEP(aa.z, 2); CSTEP(aa.w, 3);
        CSTEP(bb.x, 4); CSTEP(bb.y, 5); CSTEP(bb.z, 6); CSTEP(bb.w, 7);
      }
    }
#pragma unroll
    for (int l = 0; l < 8; ++l)
      pool[l >> 1] += fmaxf(s0[l] + bias, 0.f) + fmaxf(s1[l] + bias, 0.f);
  }
#undef CSTEP
#pragma unroll
  for (int lb = 0; lb < 4; ++lb) red[rowgrp][lb * 16 + co] = pool[lb];
  __syncthreads();
  if (t < 64) {
    float s = 0.f;
#pragma unroll
    for (int rg = 0; rg < 16; ++rg) s += red[rg][t];
    int rb = sub >> 6, subW = sub & 63;
    gPartial[(((size_t)(b * 4 + rb) * 64 + subW) * 64) + t] = s;
  }
}

// deterministic stage-2 reduce -> flat [B][256] (order ch*16 + rb*4 + lb)
__global__ void c2p2(const float* __restrict__ gPartial, float* __restrict__ flatS) {
  int b = blockIdx.x; int t = threadIdx.x;
  int ch = t >> 4; int rb = (t >> 2) & 3; int lb = t & 3;
  float s = 0.f;
  for (int sub = 0; sub < 64; ++sub)
    s += gPartial[(((size_t)(b * 4 + rb) * 64 + sub) * 64) + lb * 16 + ch];
  flatS[b * 256 + t] = s * (1.0f / 12288.0f);
}

// ---------------- projection GEMV fused with sort-2 key build ----------------
__global__ __launch_bounds__(256) void proj_k(const float* __restrict__ flatS, const float* __restrict__ pw,
                                              const float* __restrict__ pb, u64* __restrict__ kv2) {
  __shared__ float fs[8][256];
  int t = threadIdx.x;
  for (int i = t; i < 2048; i += 256) fs[i >> 8][i & 255] = flatS[i];
  __syncthreads();
  int q = t & 15; int og = t >> 4;
  int o = blockIdx.x * 16 + og;
  float acc[8];
#pragma unroll
  for (int b = 0; b < 8; ++b) acc[b] = 0.f;
  const float* wr = pw + (size_t)o * 256;
#pragma unroll
  for (int j = 0; j < 16; ++j) {
    float w = wr[q + 16 * j];
#pragma unroll
    for (int b = 0; b < 8; ++b) acc[b] = fmaf(fs[b][q + 16 * j], w, acc[b]);
  }
#pragma unroll
  for (int m = 1; m < 16; m <<= 1)
#pragma unroll
    for (int b = 0; b < 8; ++b) acc[b] += __shfl_xor(acc[b], m, 64);
  if (q == 0) {
    float bias = pb[o];
#pragma unroll
    for (int b = 0; b < 8; ++b) {
      u32 k = fkey(acc[b] + bias);
      kv2[(size_t)b * NOPS_ + o] = ((u64)k << 32) | (u32)o;
    }
  }
}

// ---------------- staged penalty (integer-exact, double accumulation) + fused final reduce ----------------
__device__ __forceinline__ double stagedp(float d) {
  double h, base;
  if (d >= 0.f) { h = (double)d; base = h; }
  else { h = (double)(-d); base = h * h; }
  double f = (h <= 2.0) ? 1.0 : (h <= 4.0) ? 1.5 : (h <= 8.0) ? 2.0 : (h <= 16.0) ? 3.0 : 5.0;
  return base * f;
}

__global__ __launch_bounds__(256) void penalty_k(const u32* __restrict__ perm, const uint4* __restrict__ addr3,
                                                 double* __restrict__ partials, u32* __restrict__ ctr,
                                                 float* __restrict__ out) {
  int b = blockIdx.x >> 6; int blk = blockIdx.x & 63;
  int t = threadIdx.x, lane = t & 63;
  const u32* pm = perm + (size_t)b * NOPS_;
  const uint4* a3 = addr3 + (size_t)b * HW_;
  double intra = 0.0, inter = 0.0;
#pragma unroll
  for (int s = 0; s < 4; ++s) {
    int tg = blk * 1024 + s * 256 + t;
    u32 p = pm[tg];
    uint4 g = a3[p];
    float a0 = (float)g.x, a1 = (float)g.y, a2 = (float)g.z;
    intra += stagedp(a1 - a0) + stagedp(a2 - a1);
    float a2p = __shfl_up(a2, 1, 64);
    if (lane == 0 && tg > 0) {
      u32 pp = pm[tg - 1];
      a2p = (float)a3[pp].z;
    }
    if (tg > 0) inter += stagedp(a0 - a2p);
  }
#pragma unroll
  for (int m = 1; m < 64; m <<= 1) {
    intra += __shfl_xor(intra, m, 64);
    inter += __shfl_xor(inter, m, 64);
  }
  __shared__ double red[4][2];
  __shared__ u32 lastFlag;
  int wid = t >> 6;
  if (lane == 0) { red[wid][0] = inter; red[wid][1] = intra; }
  __syncthreads();
  if (t == 0) {
    double i0 = red[0][0] + red[1][0] + red[2][0] + red[3][0];
    double i1 = red[0][1] + red[1][1] + red[2][1] + red[3][1];
    partials[((size_t)b * 64 + blk) * 2 + 0] = i0;
    partials[((size_t)b * 64 + blk) * 2 + 1] = i1;
    __threadfence();
    u32 done = atomicAdd(ctr, 1u);
    lastFlag = (done == (u32)(BN * 64 - 1));
  }
  __syncthreads();
  if (lastFlag) {
    __threadfence();
    if (t < 16) {
      int which = t >> 3, bb = t & 7;
      double s = 0.0;
      for (int k = 0; k < 64; ++k) s += partials[((size_t)bb * 64 + k) * 2 + which];
      out[which * 8 + bb] = (float)s;
    }
  }
}

// ---------------- host ----------------
extern "C" void kernel_launch(void* const* d_in, const int* in_sizes, int n_in,
                              void* d_out, int out_size, void* d_ws, size_t ws_size,
                              hipStream_t stream) {
  const float* logits = (const float*)d_in[0];
  const float* w1 = (const float*)d_in[1];
  const float* b1 = (const float*)d_in[2];
  const float* w2 = (const float*)d_in[3];
  const float* b2 = (const float*)d_in[4];
  const float* pw = (const float*)d_in[5];
  const float* pb = (const float*)d_in[6];
  float* out = (float*)d_out;

  char* ws = (char*)d_ws;
  size_t o = 0;
  auto take = [&](size_t bytes) { char* p = ws + o; o += (bytes + 255) & ~(size_t)255; return p; };
  u64* kv1A = (u64*)take((size_t)BN * N1 * 8);
  u64* kv1B = (u64*)take((size_t)BN * N1 * 8);
  u64* kv2A = (u64*)take((size_t)BN * NOPS_ * 8);
  u64* kv2B = (u64*)take((size_t)BN * NOPS_ * 8);
  u32* hist = (u32*)take((size_t)256 * NB1 * BN * 4);
  u32* gTotAll = (u32*)take(((size_t)8 * BN * 256 + 64) * 4);   // + ctr slot
  u32* addr = (u32*)take((size_t)BN * N1 * 4);
  float* mem = (float*)take((size_t)BN * N1 * 8 * 4);
  float* gPartial = (float*)take((size_t)BN * 4 * 64 * 64 * 4);
  float* flatS = (float*)take((size_t)BN * 256 * 4);
  u32* perm = (u32*)take((size_t)BN * NOPS_ * 4);
  double* partials = (double*)take((size_t)BN * 64 * 2 * 8);
  uint4* addr3 = (uint4*)kv1A;                  // alias: kv1A dead after sort-1 pass 2
  u32* ctr = gTotAll + (size_t)8 * BN * 256;    // zeroed by the memset below

  hipMemsetAsync(gTotAll, 0, ((size_t)8 * BN * 256 + 64) * 4, stream);

  // sort 1: stable argsort of mem_logits (pass 0 builds keys from logits on the fly)
  {
    u32* gT = gTotAll;
    rs_hist<true><<<BN * NB1, 256, 0, stream>>>(nullptr, logits, hist, gT, N1, NB1, 0);
    rs_scanB<<<BN * 64, 256, 0, stream>>>(hist, gT, NB1);
    rs_scatter<true, false><<<BN * NB1, 256, 0, stream>>>(nullptr, logits, kv1B, nullptr, hist, N1, NB1, 0);
  }
  u64* src = kv1B; u64* dst = kv1A;
  for (int p = 1; p < 4; ++p) {
    u32* gT = gTotAll + (size_t)p * BN * 256;
    rs_hist<false><<<BN * NB1, 256, 0, stream>>>(src, nullptr, hist, gT, N1, NB1, p * 8);
    rs_scanB<<<BN * 64, 256, 0, stream>>>(hist, gT, NB1);
    if (p < 3) {
      rs_scatter<false, false><<<BN * NB1, 256, 0, stream>>>(src, nullptr, dst, nullptr, hist, N1, NB1, p * 8);
      u64* tmp = src; src = dst; dst = tmp;
    } else {
      rs_scatter<false, true><<<BN * NB1, 256, 0, stream>>>(src, nullptr, nullptr, addr, hist, N1, NB1, p * 8);
    }
  }

  // conv1 + permutation scatter into mem [B][N1][8]; k==0 blocks also build addr3
  conv1_scatter<<<BN * 3 * 64, 256, 0, stream>>>(addr, w1, b1, mem, addr3);

  // conv2 + adaptive pool (two-stage deterministic reduction)
  c2p1<<<BN * 256, 256, 0, stream>>>(mem, w2, b2, gPartial);
  c2p2<<<BN, 256, 0, stream>>>(gPartial, flatS);

  // projection GEMV (+ sort-2 key build)
  proj_k<<<NOPS_ / 16, 256, 0, stream>>>(flatS, pw, pb, kv2A);

  // sort 2: stable argsort of op_logits
  src = kv2A; dst = kv2B;
  for (int p = 0; p < 4; ++p) {
    u32* gT = gTotAll + (size_t)(4 + p) * BN * 256;
    rs_hist<false><<<BN * NB2, 256, 0, stream>>>(src, nullptr, hist, gT, NOPS_, NB2, p * 8);
    rs_scanB<<<BN * 64, 256, 0, stream>>>(hist, gT, NB2);
    if (p < 3) {
      rs_scatter<false, false><<<BN * NB2, 256, 0, stream>>>(src, nullptr, dst, nullptr, hist, NOPS_, NB2, p * 8);
      u64* tmp = src; src = dst; dst = tmp;
    } else {
      rs_scatter<false, true><<<BN * NB2, 256, 0, stream>>>(src, nullptr, nullptr, perm, hist, NOPS_, NB2, p * 8);
    }
  }

  // staged penalties + fused final reduce (last-block pattern)
  penalty_k<<<BN * 64, 256, 0, stream>>>(perm, addr3, partials, ctr, out);
}

// Round 12
// 270.289 us; speedup vs baseline: 1.3875x; 1.0707x over previous
//
#include <hip/hip_runtime.h>
#include <stdint.h>

typedef unsigned int u32;
typedef unsigned long long u64;

#define BN 8
#define HW_ 65536
#define N1 196608
#define NOPS_ 65536
#define NROWS_ 24576
#define NB1 96
#define NB2 64

// ---------------- sort key transform ----------------
__device__ __forceinline__ u32 fkey(float x) {
  u32 u = __float_as_uint(x);
  return u ^ ((u & 0x80000000u) ? 0xFFFFFFFFu : 0x80000000u);
}

// ---------------- radix pass: histogram (STRIPS*256 items/block) + global digit totals ----------------
// non-FIRST reads only the HIGH DWORD of each u64 item (halves key-read bytes)
template <bool FIRST, int STRIPS>
__global__ __launch_bounds__(256) void rs_hist(const u64* __restrict__ kv, const float* __restrict__ xf,
                                               u32* __restrict__ hist, u32* __restrict__ gTot,
                                               int n, int nblk, int shift) {
  __shared__ u32 h[256];
  int t = threadIdx.x;
  int b = blockIdx.x / nblk, blk = blockIdx.x % nblk;
  h[t] = 0;
  __syncthreads();
  if (FIRST) {
    const float* xp = xf + (size_t)b * n + (size_t)blk * (STRIPS * 256);
#pragma unroll
    for (int j = 0; j < STRIPS; ++j) {
      u32 d = fkey(xp[j * 256 + t]) & 255u;
      atomicAdd(&h[d], 1u);
    }
  } else {
    const u32* kp32 = (const u32*)(kv + (size_t)b * n + (size_t)blk * (STRIPS * 256));
#pragma unroll
    for (int j = 0; j < STRIPS; ++j) {
      u32 hi = kp32[2 * (j * 256 + t) + 1];
      u32 d = (hi >> shift) & 255u;
      atomicAdd(&h[d], 1u);
    }
  }
  __syncthreads();
  hist[((size_t)b * 256 + t) * nblk + blk] = h[t];
  atomicAdd(&gTot[b * 256 + t], h[t]);   // per-digit atomics: order-independent -> deterministic
}

// ---------------- wave-parallel scan helpers ----------------
__device__ __forceinline__ u32 wscan_incl(u32 x, int lane) {
#pragma unroll
  for (int off = 1; off < 64; off <<= 1) {
    u32 y = __shfl_up(x, off, 64);
    if (lane >= off) x += y;
  }
  return x;
}

// per-digit block-offset scan, with digit base folded in. grid = BN*64, 256 thr (wave = one digit)
// guarded for nblk not a multiple of 64
__global__ __launch_bounds__(256) void rs_scanB(u32* __restrict__ hist, const u32* __restrict__ gTot, int nblk) {
  int t = threadIdx.x, w = t >> 6, lane = t & 63;
  int b = blockIdx.x >> 6, dgrp = blockIdx.x & 63;
  int d = dgrp * 4 + w;
  const u32* gt = gTot + b * 256;
  u32 base = 0, run = 0;
  int dc = d >> 6, dl = d & 63;
#pragma unroll
  for (int c = 0; c < 4; ++c) {
    u32 v = gt[c * 64 + lane];
    u32 incl = wscan_incl(v, lane);
    if (c == dc) base = run + __shfl(incl - v, dl, 64);
    run += __shfl(incl, 63, 64);
  }
  u32* p = hist + ((size_t)b * 256 + d) * nblk;
  u32 acc = base;
  for (int c = 0; c < nblk; c += 64) {
    bool ok = (c + lane) < nblk;
    u32 v = ok ? p[c + lane] : 0u;
    u32 incl = wscan_incl(v, lane);
    if (ok) p[c + lane] = acc + incl - v;
    acc += __shfl(incl, 63, 64);
  }
}

// ---------------- stable scatter v5: LDS-staged digit-sorted writes (coalesced) ----------------
template <bool FIRST, bool FINAL, int STRIPS>
__global__ __launch_bounds__(256) void rs_scatter(const u64* __restrict__ kvIn, const float* __restrict__ xf,
                                                  u64* __restrict__ out64, u32* __restrict__ out32,
                                                  const u32* __restrict__ hist, int n, int nblk, int shift) {
  __shared__ u32 sBase[256];
  __shared__ u32 cnt[STRIPS * 4][256];   // [strip*4+wave][digit]
  __shared__ u32 dpre[256];              // block-local exclusive digit prefix
  __shared__ u32 wsum[4];
  __shared__ u64 stage[STRIPS * 256];
  int t = threadIdx.x, lane = t & 63, wid = t >> 6;
  int b = blockIdx.x / nblk, blk = blockIdx.x % nblk;
  u64 kvr[STRIPS]; u32 dg[STRIPS];
  if (FIRST) {
    const float* xp = xf + (size_t)b * n + (size_t)blk * (STRIPS * 256);
#pragma unroll
    for (int j = 0; j < STRIPS; ++j) {
      u32 k = fkey(xp[j * 256 + t]);
      kvr[j] = ((u64)k << 32) | (u32)(blk * (STRIPS * 256) + j * 256 + t);
      dg[j] = k & 255u;
    }
  } else {
    const u64* kp = kvIn + (size_t)b * n + (size_t)blk * (STRIPS * 256);
#pragma unroll
    for (int j = 0; j < STRIPS; ++j) {
      kvr[j] = kp[j * 256 + t];
      dg[j] = (u32)(kvr[j] >> (32 + shift)) & 255u;
    }
  }
  sBase[t] = hist[((size_t)b * 256 + t) * nblk + blk];
#pragma unroll
  for (int r = 0; r < STRIPS * 4; ++r) cnt[r][t] = 0;
  __syncthreads();
  u64 lmask = (1ull << lane) - 1ull;
  u32 rw[STRIPS];
#pragma unroll
  for (int j = 0; j < STRIPS; ++j) {
    u32 d = dg[j];
    u64 peers = ~0ull;
#pragma unroll
    for (int bit = 0; bit < 8; ++bit) {
      u64 bal = __ballot((d >> bit) & 1);
      peers &= ((d >> bit) & 1) ? bal : ~bal;
    }
    u64 lower = peers & lmask;
    rw[j] = (u32)__popcll(lower);
    if (lower == 0) cnt[j * 4 + wid][d] = (u32)__popcll(peers);
  }
  __syncthreads();
  // thread t owns digit t: local prefix in item order (strip, wave) -> stability
  u32 run = 0;
#pragma unroll
  for (int r = 0; r < STRIPS * 4; ++r) { u32 c = cnt[r][t]; cnt[r][t] = run; run += c; }
  // block-wide exclusive digit prefix
  u32 incl = wscan_incl(run, lane);
  if (lane == 63) wsum[wid] = incl;
  __syncthreads();
  u32 woff = 0;
#pragma unroll
  for (int w = 0; w < 4; ++w) if (w < wid) woff += wsum[w];
  dpre[t] = woff + incl - run;
  __syncthreads();
  // stage into LDS in digit-sorted (final) order
#pragma unroll
  for (int j = 0; j < STRIPS; ++j) {
    u32 d = dg[j];
    u32 lpos = dpre[d] + cnt[j * 4 + wid][d] + rw[j];
    stage[lpos] = kvr[j];
  }
  __syncthreads();
  // coalesced write-out
#pragma unroll
  for (int s = 0; s < STRIPS; ++s) {
    int i = s * 256 + t;
    u64 kv = stage[i];
    u32 d = (u32)(kv >> (32 + shift)) & 255u;
    u32 g = sBase[d] + ((u32)i - dpre[d]);
    if (FINAL) out32[(size_t)b * n + g] = (u32)kv;
    else out64[(size_t)b * n + g] = kv;
  }
}

// ---------------- conv1 (grouped 1->8, 3x3 SAME) + permutation scatter + addr3 build (k==0) ----------------
__global__ __launch_bounds__(256) void conv1_scatter(const u32* __restrict__ addr, const float* __restrict__ w1,
                                                     const float* __restrict__ b1, float* __restrict__ mem,
                                                     uint4* __restrict__ addr3) {
  __shared__ float ax[34][34];
  __shared__ float ws[8][9];
  __shared__ float bs[8];
  int t = threadIdx.x;
  int blk = blockIdx.x;
  int tile = blk & 63; int bk2 = blk >> 6; int k = bk2 % 3; int b = bk2 / 3;
  int ty = tile >> 3, tx = tile & 7;
  if (t < 72) ws[t / 9][t % 9] = w1[k * 72 + t];
  if (t >= 128 && t < 136) bs[t - 128] = b1[k * 8 + (t - 128)];
  const u32* ap = addr + (size_t)b * N1 + (size_t)k * HW_;
  for (int idx = t; idx < 34 * 34; idx += 256) {
    int y = idx / 34, x = idx % 34;
    int h = ty * 32 + y - 1, w = tx * 32 + x - 1;
    float v = 0.f;
    if (h >= 0 && h < 256 && w >= 0 && w < 256) v = (float)ap[h * 256 + w];
    ax[y][x] = v;
  }
  __syncthreads();
  float* mb = mem + (size_t)b * N1 * 8;
  const u32* adb = addr + (size_t)b * N1;
  uint4* a3b = addr3 + (size_t)b * HW_;
#pragma unroll
  for (int s = 0; s < 4; ++s) {
    int p = t + s * 256;
    int y = p >> 5, x = p & 31;
    float f[8];
#pragma unroll
    for (int c = 0; c < 8; ++c) f[c] = bs[c];
#pragma unroll
    for (int dy = 0; dy < 3; ++dy)
#pragma unroll
      for (int dx = 0; dx < 3; ++dx) {
        float v = ax[y + dy][x + dx];
#pragma unroll
        for (int c = 0; c < 8; ++c) f[c] = fmaf(ws[c][dy * 3 + dx], v, f[c]);
      }
    u32 a = (u32)ax[y + 1][x + 1];
    float4* dst = reinterpret_cast<float4*>(mb + (size_t)a * 8);
    float4 lo = make_float4(fmaxf(f[0], 0.f), fmaxf(f[1], 0.f), fmaxf(f[2], 0.f), fmaxf(f[3], 0.f));
    float4 hi = make_float4(fmaxf(f[4], 0.f), fmaxf(f[5], 0.f), fmaxf(f[6], 0.f), fmaxf(f[7], 0.f));
    dst[0] = lo; dst[1] = hi;
    if (k == 0) {
      int gp = (ty * 32 + y) * 256 + tx * 32 + x;
      a3b[gp] = make_uint4(a, adb[HW_ + gp], adb[2 * HW_ + gp], 0u);
    }
  }
}

// ---------------- conv2 + pool (proven 55 us version, no fusion) ----------------
__global__ __launch_bounds__(256, 3) void c2p1(const float* __restrict__ mem, const float* __restrict__ w2,
                                               const float* __restrict__ b2, float* __restrict__ gPartial) {
  __shared__ float tile[98 * 68];
  __shared__ float w2s[1152];
  __shared__ float b2s[16];
  __shared__ float red[16][64];
  int blk = blockIdx.x; int sub = blk & 255; int b = blk >> 8;
  int r0 = sub * 96;
  int t = threadIdx.x;
  for (int idx = t; idx < 1152; idx += 256) w2s[idx] = w2[idx];
  if (t < 16) b2s[t] = b2[t];
  const float* mb = mem + (size_t)b * (N1 * 8);
  for (int q = t; q < 98 * 16; q += 256) {
    int ti = q >> 4, qw = q & 15;
    int r = r0 - 1 + ti;
    float4 v = make_float4(0.f, 0.f, 0.f, 0.f);
    if (r >= 0 && r < NROWS_) v = *reinterpret_cast<const float4*>(mb + (size_t)r * 64 + qw * 4);
    *reinterpret_cast<float4*>(&tile[ti * 68 + qw * 4]) = v;
  }
  __syncthreads();
  int co = t & 15, rowgrp = t >> 4;
  float wreg[3][3][8];
#pragma unroll
  for (int ci = 0; ci < 8; ++ci)
#pragma unroll
    for (int kr = 0; kr < 3; ++kr)
#pragma unroll
      for (int kc = 0; kc < 3; ++kc)
        wreg[kr][kc][ci] = w2s[(co * 8 + ci) * 9 + kr * 3 + kc];
  float bias = b2s[co];
  float pool[4] = {0.f, 0.f, 0.f, 0.f};
#define CSTEP(V, CI) do { \
    if (j < 3) { \
      if (li >= 1) s0[li - 1] = fmaf((V), wreg[j][2][CI], s0[li - 1]); \
      s0[li] = fmaf((V), wreg[j][1][CI], s0[li]); \
      if (li < 7) s0[li + 1] = fmaf((V), wreg[j][0][CI], s0[li + 1]); \
    } \
    if (j >= 1) { \
      if (li >= 1) s1[li - 1] = fmaf((V), wreg[j - 1][2][CI], s1[li - 1]); \
      s1[li] = fmaf((V), wreg[j - 1][1][CI], s1[li]); \
      if (li < 7) s1[li + 1] = fmaf((V), wreg[j - 1][0][CI], s1[li + 1]); \
    } \
  } while (0)
#pragma unroll 1
  for (int i = 0; i < 3; ++i) {
    int lr0 = rowgrp * 2 + 32 * i;
    float s0[8], s1[8];
#pragma unroll
    for (int l = 0; l < 8; ++l) { s0[l] = 0.f; s1[l] = 0.f; }
#pragma unroll
    for (int j = 0; j < 4; ++j) {
      const float* trow = &tile[(lr0 + j) * 68];
#pragma unroll
      for (int li = 0; li < 8; ++li) {
        float4 aa = *reinterpret_cast<const float4*>(trow + li * 8);
        float4 bb = *reinterpret_cast<const float4*>(trow + li * 8 + 4);
        CSTEP(aa.x, 0); CSTEP(aa.y, 1); CSTEP(aa.z, 2); CSTEP(aa.w, 3);
        CSTEP(bb.x, 4); CSTEP(bb.y, 5); CSTEP(bb.z, 6); CSTEP(bb.w, 7);
      }
    }
#pragma unroll
    for (int l = 0; l < 8; ++l)
      pool[l >> 1] += fmaxf(s0[l] + bias, 0.f) + fmaxf(s1[l] + bias, 0.f);
  }
#undef CSTEP
#pragma unroll
  for (int lb = 0; lb < 4; ++lb) red[rowgrp][lb * 16 + co] = pool[lb];
  __syncthreads();
  if (t < 64) {
    float s = 0.f;
#pragma unroll
    for (int rg = 0; rg < 16; ++rg) s += red[rg][t];
    int rb = sub >> 6, subW = sub & 63;
    gPartial[(((size_t)(b * 4 + rb) * 64 + subW) * 64) + t] = s;
  }
}

// deterministic stage-2 reduce -> flat [B][256] (order ch*16 + rb*4 + lb)
__global__ void c2p2(const float* __restrict__ gPartial, float* __restrict__ flatS) {
  int b = blockIdx.x; int t = threadIdx.x;
  int ch = t >> 4; int rb = (t >> 2) & 3; int lb = t & 3;
  float s = 0.f;
  for (int sub = 0; sub < 64; ++sub)
    s += gPartial[(((size_t)(b * 4 + rb) * 64 + sub) * 64) + lb * 16 + ch];
  flatS[b * 256 + t] = s * (1.0f / 12288.0f);
}

// ---------------- projection GEMV fused with sort-2 key build ----------------
__global__ __launch_bounds__(256) void proj_k(const float* __restrict__ flatS, const float* __restrict__ pw,
                                              const float* __restrict__ pb, u64* __restrict__ kv2) {
  __shared__ float fs[8][256];
  int t = threadIdx.x;
  for (int i = t; i < 2048; i += 256) fs[i >> 8][i & 255] = flatS[i];
  __syncthreads();
  int q = t & 15; int og = t >> 4;
  int o = blockIdx.x * 16 + og;
  float acc[8];
#pragma unroll
  for (int b = 0; b < 8; ++b) acc[b] = 0.f;
  const float* wr = pw + (size_t)o * 256;
#pragma unroll
  for (int j = 0; j < 16; ++j) {
    float w = wr[q + 16 * j];
#pragma unroll
    for (int b = 0; b < 8; ++b) acc[b] = fmaf(fs[b][q + 16 * j], w, acc[b]);
  }
#pragma unroll
  for (int m = 1; m < 16; m <<= 1)
#pragma unroll
    for (int b = 0; b < 8; ++b) acc[b] += __shfl_xor(acc[b], m, 64);
  if (q == 0) {
    float bias = pb[o];
#pragma unroll
    for (int b = 0; b < 8; ++b) {
      u32 k = fkey(acc[b] + bias);
      kv2[(size_t)b * NOPS_ + o] = ((u64)k << 32) | (u32)o;
    }
  }
}

// ---------------- staged penalty (integer-exact, double accumulation) + fused final reduce ----------------
__device__ __forceinline__ double stagedp(float d) {
  double h, base;
  if (d >= 0.f) { h = (double)d; base = h; }
  else { h = (double)(-d); base = h * h; }
  double f = (h <= 2.0) ? 1.0 : (h <= 4.0) ? 1.5 : (h <= 8.0) ? 2.0 : (h <= 16.0) ? 3.0 : 5.0;
  return base * f;
}

__global__ __launch_bounds__(256) void penalty_k(const u32* __restrict__ perm, const uint4* __restrict__ addr3,
                                                 double* __restrict__ partials, u32* __restrict__ ctr,
                                                 float* __restrict__ out) {
  int b = blockIdx.x >> 6; int blk = blockIdx.x & 63;
  int t = threadIdx.x, lane = t & 63;
  const u32* pm = perm + (size_t)b * NOPS_;
  const uint4* a3 = addr3 + (size_t)b * HW_;
  double intra = 0.0, inter = 0.0;
#pragma unroll
  for (int s = 0; s < 4; ++s) {
    int tg = blk * 1024 + s * 256 + t;
    u32 p = pm[tg];
    uint4 g = a3[p];
    float a0 = (float)g.x, a1 = (float)g.y, a2 = (float)g.z;
    intra += stagedp(a1 - a0) + stagedp(a2 - a1);
    float a2p = __shfl_up(a2, 1, 64);
    if (lane == 0 && tg > 0) {
      u32 pp = pm[tg - 1];
      a2p = (float)a3[pp].z;
    }
    if (tg > 0) inter += stagedp(a0 - a2p);
  }
#pragma unroll
  for (int m = 1; m < 64; m <<= 1) {
    intra += __shfl_xor(intra, m, 64);
    inter += __shfl_xor(inter, m, 64);
  }
  __shared__ double red[4][2];
  __shared__ u32 lastFlag;
  int wid = t >> 6;
  if (lane == 0) { red[wid][0] = inter; red[wid][1] = intra; }
  __syncthreads();
  if (t == 0) {
    double i0 = red[0][0] + red[1][0] + red[2][0] + red[3][0];
    double i1 = red[0][1] + red[1][1] + red[2][1] + red[3][1];
    partials[((size_t)b * 64 + blk) * 2 + 0] = i0;
    partials[((size_t)b * 64 + blk) * 2 + 1] = i1;
    __threadfence();
    u32 done = atomicAdd(ctr, 1u);
    lastFlag = (done == (u32)(BN * 64 - 1));
  }
  __syncthreads();
  if (lastFlag) {
    __threadfence();
    if (t < 16) {
      int which = t >> 3, bb = t & 7;
      double s = 0.0;
      for (int k = 0; k < 64; ++k) s += partials[((size_t)bb * 64 + k) * 2 + which];
      out[which * 8 + bb] = (float)s;
    }
  }
}

// ---------------- host ----------------
extern "C" void kernel_launch(void* const* d_in, const int* in_sizes, int n_in,
                              void* d_out, int out_size, void* d_ws, size_t ws_size,
                              hipStream_t stream) {
  const float* logits = (const float*)d_in[0];
  const float* w1 = (const float*)d_in[1];
  const float* b1 = (const float*)d_in[2];
  const float* w2 = (const float*)d_in[3];
  const float* b2 = (const float*)d_in[4];
  const float* pw = (const float*)d_in[5];
  const float* pb = (const float*)d_in[6];
  float* out = (float*)d_out;

  char* ws = (char*)d_ws;
  size_t o = 0;
  auto take = [&](size_t bytes) { char* p = ws + o; o += (bytes + 255) & ~(size_t)255; return p; };
  u64* kv1A = (u64*)take((size_t)BN * N1 * 8);
  u64* kv1B = (u64*)take((size_t)BN * N1 * 8);
  u64* kv2A = (u64*)take((size_t)BN * NOPS_ * 8);
  u64* kv2B = (u64*)take((size_t)BN * NOPS_ * 8);
  u32* hist = (u32*)take((size_t)256 * NB1 * BN * 4);
  u32* gTotAll = (u32*)take(((size_t)8 * BN * 256 + 64) * 4);   // + ctr slot
  u32* addr = (u32*)take((size_t)BN * N1 * 4);
  float* mem = (float*)take((size_t)BN * N1 * 8 * 4);
  float* gPartial = (float*)take((size_t)BN * 4 * 64 * 64 * 4);
  float* flatS = (float*)take((size_t)BN * 256 * 4);
  u32* perm = (u32*)take((size_t)BN * NOPS_ * 4);
  double* partials = (double*)take((size_t)BN * 64 * 2 * 8);
  uint4* addr3 = (uint4*)kv1A;                  // alias: kv1A dead after sort-1 pass 2
  u32* ctr = gTotAll + (size_t)8 * BN * 256;    // zeroed by the memset below

  hipMemsetAsync(gTotAll, 0, ((size_t)8 * BN * 256 + 64) * 4, stream);

  // sort 1: stable argsort of mem_logits (2048-item tiles; pass 0 builds keys from logits)
  {
    u32* gT = gTotAll;
    rs_hist<true, 8><<<BN * NB1, 256, 0, stream>>>(nullptr, logits, hist, gT, N1, NB1, 0);
    rs_scanB<<<BN * 64, 256, 0, stream>>>(hist, gT, NB1);
    rs_scatter<true, false, 8><<<BN * NB1, 256, 0, stream>>>(nullptr, logits, kv1B, nullptr, hist, N1, NB1, 0);
  }
  u64* src = kv1B; u64* dst = kv1A;
  for (int p = 1; p < 4; ++p) {
    u32* gT = gTotAll + (size_t)p * BN * 256;
    rs_hist<false, 8><<<BN * NB1, 256, 0, stream>>>(src, nullptr, hist, gT, N1, NB1, p * 8);
    rs_scanB<<<BN * 64, 256, 0, stream>>>(hist, gT, NB1);
    if (p < 3) {
      rs_scatter<false, false, 8><<<BN * NB1, 256, 0, stream>>>(src, nullptr, dst, nullptr, hist, N1, NB1, p * 8);
      u64* tmp = src; src = dst; dst = tmp;
    } else {
      rs_scatter<false, true, 8><<<BN * NB1, 256, 0, stream>>>(src, nullptr, nullptr, addr, hist, N1, NB1, p * 8);
    }
  }

  // conv1 + permutation scatter into mem [B][N1][8]; k==0 blocks also build addr3
  conv1_scatter<<<BN * 3 * 64, 256, 0, stream>>>(addr, w1, b1, mem, addr3);

  // conv2 + adaptive pool (two-stage deterministic reduction)
  c2p1<<<BN * 256, 256, 0, stream>>>(mem, w2, b2, gPartial);
  c2p2<<<BN, 256, 0, stream>>>(gPartial, flatS);

  // projection GEMV (+ sort-2 key build)
  proj_k<<<NOPS_ / 16, 256, 0, stream>>>(flatS, pw, pb, kv2A);

  // sort 2: stable argsort of op_logits (1024-item tiles)
  src = kv2A; dst = kv2B;
  for (int p = 0; p < 4; ++p) {
    u32* gT = gTotAll + (size_t)(4 + p) * BN * 256;
    rs_hist<false, 4><<<BN * NB2, 256, 0, stream>>>(src, nullptr, hist, gT, NOPS_, NB2, p * 8);
    rs_scanB<<<BN * 64, 256, 0, stream>>>(hist, gT, NB2);
    if (p < 3) {
      rs_scatter<false, false, 4><<<BN * NB2, 256, 0, stream>>>(src, nullptr, dst, nullptr, hist, NOPS_, NB2, p * 8);
      u64* tmp = src; src = dst; dst = tmp;
    } else {
      rs_scatter<false, true, 4><<<BN * NB2, 256, 0, stream>>>(src, nullptr, nullptr, perm, hist, NOPS_, NB2, p * 8);
    }
  }

  // staged penalties + fused final reduce (last-block pattern)
  penalty_k<<<BN * 64, 256, 0, stream>>>(perm, addr3, partials, ctr, out);
}